// Round 1
// baseline (563.203 us; speedup 1.0000x reference)
//
#include <hip/hip_runtime.h>
#include <math.h>
#include <float.h>

#define B_ 64
#define S_ 512
#define N_ 256
#define P_ 96
#define D_ 64
#define WIN_ 24
#define L_ 488   // S_ - WIN_
#define MID_ 7

// workspace layout (in floats)
#define OFF_XS   ((size_t)0)                        // season [B][L][N]
#define OFF_TRT  (OFF_XS  + (size_t)B_*L_*N_)       // trend^T [N][B][L]
#define OFF_ET   (OFF_TRT + (size_t)N_*B_*L_)       // embed_t [B][L][D]
#define OFF_EN   (OFF_ET  + (size_t)B_*L_*D_)       // embed_next [B][P][D]
#define OFF_WSE  (OFF_EN  + (size_t)B_*P_*D_)       // season weights [B][P][L]
#define OFF_WM   (OFF_WSE + (size_t)B_*P_*L_)       // mid weights [B][MID][L]

// ---------------- Kernel 1: rolling-mean trend + season ----------------
// grid (B, 8), block 256 (thread = n). Each block covers 61 time steps.
__global__ __launch_bounds__(256) void k_trend(const float* __restrict__ X,
                                               float* __restrict__ ws) {
    int b = blockIdx.x, tile = blockIdx.y, n = threadIdx.x;
    float* Xs  = ws + OFF_XS;
    float* trT = ws + OFF_TRT;
    const float* Xb = X + (size_t)b * S_ * N_ + n;
    int s1 = WIN_ + tile * 61;
    float wsum = 0.f;
    for (int s = s1 - WIN_; s < s1; ++s) wsum += Xb[(size_t)s * N_];
    for (int i = 0; i < 61; ++i) {
        int s = s1 + i, l = s - WIN_;
        float xv = Xb[(size_t)s * N_];
        wsum += xv - Xb[(size_t)(s - WIN_) * N_];
        float tr = wsum * (1.f / WIN_);
        Xs[((size_t)b * L_ + l) * N_ + n] = xv - tr;            // coalesced
        trT[(size_t)n * B_ * L_ + (size_t)b * L_ + l] = tr;     // per-lane sequential
    }
}

// ---------------- Kernel 2: pred_trend = einsum('npl,bln->bpn') + b_t --------
// grid (N), block 256. C[p][b] (96x64) per n; k-chunks of 32 in LDS.
__global__ __launch_bounds__(256) void k_trend_gemm(const float* __restrict__ Wt_g,
                                                    const float* __restrict__ bt,
                                                    const float* __restrict__ ws,
                                                    float* __restrict__ out0) {
    int n = blockIdx.x, tid = threadIdx.x;
    __shared__ float Wl[96][36];
    __shared__ float Bl[64][36];
    const float* trT = ws + OFF_TRT + (size_t)n * B_ * L_;
    const float* Wn  = Wt_g + (size_t)n * P_ * L_;
    int pt = tid >> 4, btl = tid & 15;
    float acc[6][4] = {};
    for (int l0 = 0; l0 < L_; l0 += 32) {
        int cur = L_ - l0; if (cur > 32) cur = 32;
        for (int idx = tid; idx < 96 * 32; idx += 256) {
            int p = idx >> 5, lc = idx & 31;
            Wl[p][lc] = (lc < cur) ? Wn[(size_t)p * L_ + l0 + lc] : 0.f;
        }
        for (int idx = tid; idx < 64 * 32; idx += 256) {
            int bb = idx >> 5, lc = idx & 31;
            Bl[bb][lc] = (lc < cur) ? trT[(size_t)bb * L_ + l0 + lc] : 0.f;
        }
        __syncthreads();
        for (int lc = 0; lc < 32; lc += 4) {
            float4 wv[6], bv[4];
#pragma unroll
            for (int j = 0; j < 6; ++j) wv[j] = *(const float4*)&Wl[pt + 16 * j][lc];
#pragma unroll
            for (int i = 0; i < 4; ++i) bv[i] = *(const float4*)&Bl[btl * 4 + i][lc];
#pragma unroll
            for (int j = 0; j < 6; ++j)
#pragma unroll
                for (int i = 0; i < 4; ++i)
                    acc[j][i] += wv[j].x * bv[i].x + wv[j].y * bv[i].y +
                                 wv[j].z * bv[i].z + wv[j].w * bv[i].w;
        }
        __syncthreads();
    }
#pragma unroll
    for (int j = 0; j < 6; ++j) {
        int p = pt + 16 * j;
        float bias = bt[(size_t)p * N_ + n];
#pragma unroll
        for (int i = 0; i < 4; ++i) {
            int bb = btl * 4 + i;
            out0[((size_t)bb * P_ + p) * N_ + n] = acc[j][i] + bias;
        }
    }
}

// ---------------- Kernel 3: time2vec embeds ----------------
__global__ __launch_bounds__(256) void k_embed(const float* __restrict__ T,
                                               const float* __restrict__ w0,
                                               const float* __restrict__ b0,
                                               const float* __restrict__ Wp,
                                               const float* __restrict__ Bp,
                                               float* __restrict__ ws) {
    int idx = blockIdx.x * 256 + threadIdx.x;
    int d = idx & 63;
    int rest = idx >> 6;
    int pos = rest % (L_ + P_);
    int b = rest / (L_ + P_);
    float t;
    float* dst;
    if (pos < L_) {
        t = T[(size_t)b * S_ + WIN_ + pos];
        dst = ws + OFF_ET + ((size_t)b * L_ + pos) * D_ + d;
    } else {
        int p = pos - L_;
        t = T[(size_t)b * S_ + (S_ - 1)] + (float)(p + 1);
        dst = ws + OFF_EN + ((size_t)b * P_ + p) * D_ + d;
    }
    float v = (d == 0) ? (t * w0[0] + b0[0]) : sinf(t * Wp[d - 1] + Bp[d - 1]);
    *dst = v;
}

// ---------------- Kernel 4a: season attention scores ----------------
// grid (B, 8 k-tiles of 64), block 256. scores[b][q][k] = q.k / 8
__global__ __launch_bounds__(256) void k_season_scores(float* ws) {
    int b = blockIdx.x, kt = blockIdx.y, tid = threadIdx.x;
    const float* EN = ws + OFF_EN + (size_t)b * P_ * D_;
    const float* ET = ws + OFF_ET + (size_t)b * L_ * D_;
    float* W = ws + OFF_WSE + (size_t)b * P_ * L_;
    __shared__ float Al[96][68];
    __shared__ float Bl[64][68];
    for (int idx = tid; idx < 96 * 64; idx += 256) Al[idx >> 6][idx & 63] = EN[idx];
    int k0 = kt * 64;
    for (int idx = tid; idx < 64 * 64; idx += 256) {
        int kk = idx >> 6, d = idx & 63;
        Bl[kk][d] = (k0 + kk < L_) ? ET[(size_t)(k0 + kk) * D_ + d] : 0.f;
    }
    __syncthreads();
    int qt = tid >> 4, ktl = tid & 15;
    float acc[6][4] = {};
    for (int d = 0; d < 64; d += 4) {
        float4 av[6], bv[4];
#pragma unroll
        for (int j = 0; j < 6; ++j) av[j] = *(const float4*)&Al[qt + 16 * j][d];
#pragma unroll
        for (int i = 0; i < 4; ++i) bv[i] = *(const float4*)&Bl[ktl * 4 + i][d];
#pragma unroll
        for (int j = 0; j < 6; ++j)
#pragma unroll
            for (int i = 0; i < 4; ++i)
                acc[j][i] += av[j].x * bv[i].x + av[j].y * bv[i].y +
                             av[j].z * bv[i].z + av[j].w * bv[i].w;
    }
    if (k0 + ktl * 4 < L_) {
#pragma unroll
        for (int j = 0; j < 6; ++j) {
            int q = qt + 16 * j;
            float4 o;
            o.x = acc[j][0] * 0.125f; o.y = acc[j][1] * 0.125f;
            o.z = acc[j][2] * 0.125f; o.w = acc[j][3] * 0.125f;
            *(float4*)&W[(size_t)q * L_ + k0 + ktl * 4] = o;
        }
    }
}

// ---------------- Kernel 4a2: softmax over 488 (season weights, in place) ----
// grid (B*P), block 64 (one wave per row)
__global__ __launch_bounds__(64) void k_softmax488(float* __restrict__ ws) {
    size_t row = blockIdx.x;
    int lane = threadIdx.x;
    float* base = ws + OFF_WSE + row * L_;
    float v[8];
    float m = -FLT_MAX;
#pragma unroll
    for (int i = 0; i < 8; ++i) {
        int idx = i * 64 + lane;
        v[i] = (idx < L_) ? base[idx] : -FLT_MAX;
        m = fmaxf(m, v[i]);
    }
    for (int off = 32; off; off >>= 1) m = fmaxf(m, __shfl_xor(m, off));
    float s = 0.f;
#pragma unroll
    for (int i = 0; i < 8; ++i) {
        float e = expf(v[i] - m);
        v[i] = e; s += e;
    }
    for (int off = 32; off; off >>= 1) s += __shfl_xor(s, off);
    float inv = 1.f / s;
#pragma unroll
    for (int i = 0; i < 8; ++i) {
        int idx = i * 64 + lane;
        if (idx < L_) base[idx] = v[i] * inv;
    }
}

// ---------------- Kernel 5a: mid attention masked scores + softmax ----------
// grid (B), block 256
__global__ __launch_bounds__(256) void k_mid_scores(float* ws) {
    int b = blockIdx.x, tid = threadIdx.x;
    const float* ET = ws + OFF_ET + (size_t)b * L_ * D_;
    float* WM = ws + OFF_WM + (size_t)b * MID_ * L_;
    __shared__ float qv[7][68];
    __shared__ float sc[7][492];
    __shared__ float red[256];
    for (int idx = tid; idx < 7 * 64; idx += 256)
        qv[idx >> 6][idx & 63] = ET[(size_t)(L_ - MID_ + (idx >> 6)) * D_ + (idx & 63)];
    __syncthreads();
    for (int k = tid; k < L_; k += 256) {
        float acc[7] = {};
        for (int d = 0; d < 64; d += 4) {
            float4 e = *(const float4*)&ET[(size_t)k * D_ + d];
#pragma unroll
            for (int q = 0; q < 7; ++q) {
                float4 qq = *(const float4*)&qv[q][d];
                acc[q] += e.x * qq.x + e.y * qq.y + e.z * qq.z + e.w * qq.w;
            }
        }
#pragma unroll
        for (int q = 0; q < 7; ++q) {
            bool valid = k < (L_ - MID_ + q);
            sc[q][k] = valid ? acc[q] * 0.125f : -FLT_MAX;
        }
    }
    __syncthreads();
    for (int q = 0; q < 7; ++q) {
        float m = -FLT_MAX;
        for (int k = tid; k < L_; k += 256) m = fmaxf(m, sc[q][k]);
        red[tid] = m; __syncthreads();
        for (int off = 128; off; off >>= 1) {
            if (tid < off) red[tid] = fmaxf(red[tid], red[tid + off]);
            __syncthreads();
        }
        float mq = red[0]; __syncthreads();
        float s = 0.f;
        for (int k = tid; k < L_; k += 256) {
            float e = expf(sc[q][k] - mq);
            sc[q][k] = e; s += e;
        }
        red[tid] = s; __syncthreads();
        for (int off = 128; off; off >>= 1) {
            if (tid < off) red[tid] += red[tid + off];
            __syncthreads();
        }
        float inv = 1.f / red[0]; __syncthreads();
        for (int k = tid; k < L_; k += 256) WM[(size_t)q * L_ + k] = sc[q][k] * inv;
    }
}

// ---------------- Kernel 4b: season PV GEMM + add trend -> out0 -------------
// grid (B, 4 n-tiles of 64), block 256. out0 already holds pred_trend.
__global__ __launch_bounds__(256) void k_season_pv(const float* __restrict__ ws,
                                                   float* __restrict__ out0) {
    int b = blockIdx.x, nt = blockIdx.y, tid = threadIdx.x;
    const float* Wb = ws + OFF_WSE + (size_t)b * P_ * L_;
    const float* Xs = ws + OFF_XS + (size_t)b * L_ * N_;
    __shared__ float Wl[96][36];
    __shared__ float Xl[32][68];
    int qt = tid >> 4, ntl = tid & 15;
    float acc[6][4] = {};
    for (int k0 = 0; k0 < L_; k0 += 32) {
        int cur = L_ - k0; if (cur > 32) cur = 32;
        for (int idx = tid; idx < 96 * 32; idx += 256) {
            int q = idx >> 5, kc = idx & 31;
            Wl[q][kc] = (kc < cur) ? Wb[(size_t)q * L_ + k0 + kc] : 0.f;
        }
        for (int idx = tid; idx < 32 * 64; idx += 256) {
            int kc = idx >> 6, nl = idx & 63;
            Xl[kc][nl] = (kc < cur) ? Xs[(size_t)(k0 + kc) * N_ + nt * 64 + nl] : 0.f;
        }
        __syncthreads();
        for (int kc = 0; kc < 32; kc += 4) {
            float4 wv[6];
#pragma unroll
            for (int j = 0; j < 6; ++j) wv[j] = *(const float4*)&Wl[qt + 16 * j][kc];
#pragma unroll
            for (int t = 0; t < 4; ++t) {
                float4 xv = *(const float4*)&Xl[kc + t][ntl * 4];
#pragma unroll
                for (int j = 0; j < 6; ++j) {
                    float w = (t == 0) ? wv[j].x : (t == 1) ? wv[j].y : (t == 2) ? wv[j].z : wv[j].w;
                    acc[j][0] += w * xv.x;
                    acc[j][1] += w * xv.y;
                    acc[j][2] += w * xv.z;
                    acc[j][3] += w * xv.w;
                }
            }
        }
        __syncthreads();
    }
#pragma unroll
    for (int j = 0; j < 6; ++j) {
        int q = qt + 16 * j;
        float4* op = (float4*)&out0[((size_t)b * P_ + q) * N_ + nt * 64 + ntl * 4];
        float4 prev = *op;
        prev.x += acc[j][0]; prev.y += acc[j][1];
        prev.z += acc[j][2]; prev.w += acc[j][3];
        *op = prev;
    }
}

// ---------------- Kernel 5b: mid PV -> out1 ----------------
// grid (B, 4 n-tiles of 64), block 256 (= 64 n x 4 k-slices)
__global__ __launch_bounds__(256) void k_mid_pv(const float* __restrict__ ws,
                                                float* __restrict__ out1) {
    int b = blockIdx.x, nt = blockIdx.y, tid = threadIdx.x;
    int nl = tid & 63, ks = tid >> 6;
    const float* Xs = ws + OFF_XS + (size_t)b * L_ * N_;
    const float* WM = ws + OFF_WM + (size_t)b * MID_ * L_;
    __shared__ float wl[7 * L_];
    __shared__ float part[4][7][64];
    for (int idx = tid; idx < 7 * L_; idx += 256) wl[idx] = WM[idx];
    __syncthreads();
    float acc[7] = {};
    int kbeg = ks * 122, kend = kbeg + 122;   // 4 * 122 = 488
    for (int k = kbeg; k < kend; ++k) {
        float xv = Xs[(size_t)k * N_ + nt * 64 + nl];
#pragma unroll
        for (int q = 0; q < 7; ++q) acc[q] += wl[q * L_ + k] * xv;
    }
#pragma unroll
    for (int q = 0; q < 7; ++q) part[ks][q][nl] = acc[q];
    __syncthreads();
    if (ks == 0) {
#pragma unroll
        for (int q = 0; q < 7; ++q) {
            float v = part[0][q][nl] + part[1][q][nl] + part[2][q][nl] + part[3][q][nl];
            out1[((size_t)b * MID_ + q) * N_ + nt * 64 + nl] = v;
        }
    }
}

extern "C" void kernel_launch(void* const* d_in, const int* in_sizes, int n_in,
                              void* d_out, int out_size, void* d_ws, size_t ws_size,
                              hipStream_t stream) {
    (void)in_sizes; (void)n_in; (void)out_size; (void)ws_size;
    const float* X  = (const float*)d_in[0];
    const float* T  = (const float*)d_in[1];
    const float* Wt = (const float*)d_in[2];
    const float* bt = (const float*)d_in[3];
    const float* w0 = (const float*)d_in[4];
    const float* b0 = (const float*)d_in[5];
    const float* Wp = (const float*)d_in[6];
    const float* Bp = (const float*)d_in[7];
    float* out = (float*)d_out;
    float* ws  = (float*)d_ws;
    float* out1 = out + (size_t)B_ * P_ * N_;

    hipLaunchKernelGGL(k_trend, dim3(B_, 8), dim3(256), 0, stream, X, ws);
    hipLaunchKernelGGL(k_embed, dim3((B_ * (L_ + P_) * D_) / 256), dim3(256), 0, stream,
                       T, w0, b0, Wp, Bp, ws);
    hipLaunchKernelGGL(k_trend_gemm, dim3(N_), dim3(256), 0, stream, Wt, bt, ws, out);
    hipLaunchKernelGGL(k_season_scores, dim3(B_, 8), dim3(256), 0, stream, ws);
    hipLaunchKernelGGL(k_softmax488, dim3(B_ * P_), dim3(64), 0, stream, ws);
    hipLaunchKernelGGL(k_mid_scores, dim3(B_), dim3(256), 0, stream, ws);
    hipLaunchKernelGGL(k_season_pv, dim3(B_, 4), dim3(256), 0, stream, ws, out);
    hipLaunchKernelGGL(k_mid_pv, dim3(B_, 4), dim3(256), 0, stream, ws, out1);
}

// Round 2
// 368.329 us; speedup vs baseline: 1.5291x; 1.5291x over previous
//
#include <hip/hip_runtime.h>
#include <math.h>
#include <float.h>

#define B_ 64
#define S_ 512
#define N_ 256
#define P_ 96
#define D_ 64
#define WIN_ 24
#define L_ 488   // S_ - WIN_
#define MID_ 7
#define PB_ (P_*B_)   // 6144

// workspace layout (in floats)
#define OFF_XS   ((size_t)0)                        // season [B][L][N]
#define OFF_TRT  (OFF_XS  + (size_t)B_*L_*N_)       // trend^T [N][B][L]
#define OFF_ET   (OFF_TRT + (size_t)N_*B_*L_)       // embed_t [B][L][D]
#define OFF_EN   (OFF_ET  + (size_t)B_*L_*D_)       // embed_next [B][P][D]
#define OFF_WSE  (OFF_EN  + (size_t)B_*P_*D_)       // season weights [B][P][L]
#define OFF_WM   (OFF_WSE + (size_t)B_*P_*L_)       // mid weights [B][MID][L]
// trend-GEMM partials alias WSE+WM (2*N*PB = 3.15M floats <= 3.22M), consumed
// by k_reduce_trend BEFORE season/mid scores write WSE/WM.
#define OFF_PART OFF_WSE

// ---------------- Kernel 1: rolling-mean trend + season ----------------
__global__ __launch_bounds__(256) void k_trend(const float* __restrict__ X,
                                               float* __restrict__ ws) {
    int b = blockIdx.x, tile = blockIdx.y, n = threadIdx.x;
    float* Xs  = ws + OFF_XS;
    float* trT = ws + OFF_TRT;
    const float* Xb = X + (size_t)b * S_ * N_ + n;
    int s1 = WIN_ + tile * 61;
    float wsum = 0.f;
    for (int s = s1 - WIN_; s < s1; ++s) wsum += Xb[(size_t)s * N_];
    for (int i = 0; i < 61; ++i) {
        int s = s1 + i, l = s - WIN_;
        float xv = Xb[(size_t)s * N_];
        wsum += xv - Xb[(size_t)(s - WIN_) * N_];
        float tr = wsum * (1.f / WIN_);
        Xs[((size_t)b * L_ + l) * N_ + n] = xv - tr;
        trT[(size_t)n * B_ * L_ + (size_t)b * L_ + l] = tr;
    }
}

// ---------------- Kernel 2: time2vec embeds ----------------
__global__ __launch_bounds__(256) void k_embed(const float* __restrict__ T,
                                               const float* __restrict__ w0,
                                               const float* __restrict__ b0,
                                               const float* __restrict__ Wp,
                                               const float* __restrict__ Bp,
                                               float* __restrict__ ws) {
    int idx = blockIdx.x * 256 + threadIdx.x;
    int d = idx & 63;
    int rest = idx >> 6;
    int pos = rest % (L_ + P_);
    int b = rest / (L_ + P_);
    float t;
    float* dst;
    if (pos < L_) {
        t = T[(size_t)b * S_ + WIN_ + pos];
        dst = ws + OFF_ET + ((size_t)b * L_ + pos) * D_ + d;
    } else {
        int p = pos - L_;
        t = T[(size_t)b * S_ + (S_ - 1)] + (float)(p + 1);
        dst = ws + OFF_EN + ((size_t)b * P_ + p) * D_ + d;
    }
    float v = (d == 0) ? (t * w0[0] + b0[0]) : sinf(t * Wp[d - 1] + Bp[d - 1]);
    *dst = v;
}

// ------- Kernel 3: trend GEMM, k-split x2, partials coalesced to ws --------
// grid (N_, 2), block 256. partial[ks][n][p*64+bb]
__global__ __launch_bounds__(256) void k_trend_gemm(const float* __restrict__ Wt_g,
                                                    const float* __restrict__ ws_c,
                                                    float* __restrict__ part) {
    int n = blockIdx.x, ks = blockIdx.y, tid = threadIdx.x;
    __shared__ float smem[6144];
    float* Wl = smem;          // [96][36]
    float* Bl = smem + 3456;   // [64][36]
    const float* trT = ws_c + OFF_TRT + (size_t)n * B_ * L_;
    const float* Wn  = Wt_g + (size_t)n * P_ * L_;
    int pt = tid >> 4, btl = tid & 15;
    float acc[6][4] = {};
    int kb = ks * 244, ke = kb + 244;
    for (int l0 = kb; l0 < ke; l0 += 32) {
        int cur = ke - l0; if (cur > 32) cur = 32;   // 32 or 20, both %4==0
        for (int idx = tid; idx < 96 * 8; idx += 256) {
            int p = idx >> 3, l4 = (idx & 7) * 4;
            float4 v = (l4 < cur) ? *(const float4*)&Wn[(size_t)p * L_ + l0 + l4]
                                  : make_float4(0.f, 0.f, 0.f, 0.f);
            *(float4*)&Wl[p * 36 + l4] = v;
        }
        for (int idx = tid; idx < 64 * 8; idx += 256) {
            int bb = idx >> 3, l4 = (idx & 7) * 4;
            float4 v = (l4 < cur) ? *(const float4*)&trT[(size_t)bb * L_ + l0 + l4]
                                  : make_float4(0.f, 0.f, 0.f, 0.f);
            *(float4*)&Bl[bb * 36 + l4] = v;
        }
        __syncthreads();
        for (int lc = 0; lc < 32; lc += 4) {
            float4 wv[6], bv[4];
#pragma unroll
            for (int j = 0; j < 6; ++j) wv[j] = *(const float4*)&Wl[(pt + 16 * j) * 36 + lc];
#pragma unroll
            for (int i = 0; i < 4; ++i) bv[i] = *(const float4*)&Bl[(btl + 16 * i) * 36 + lc];
#pragma unroll
            for (int j = 0; j < 6; ++j)
#pragma unroll
                for (int i = 0; i < 4; ++i)
                    acc[j][i] += wv[j].x * bv[i].x + wv[j].y * bv[i].y +
                                 wv[j].z * bv[i].z + wv[j].w * bv[i].w;
        }
        __syncthreads();
    }
    // stage C into LDS, write coalesced
    float* Cst = smem;
#pragma unroll
    for (int j = 0; j < 6; ++j)
#pragma unroll
        for (int i = 0; i < 4; ++i)
            Cst[(pt + 16 * j) * 64 + (btl + 16 * i)] = acc[j][i];
    __syncthreads();
    float4* dst = (float4*)(part + ((size_t)ks * N_ + n) * PB_);
    const float4* src = (const float4*)Cst;
    for (int i = tid; i < PB_ / 4; i += 256) dst[i] = src[i];
}

// ------- Kernel 4: reduce partials + bias, transpose to out0 [b][p][n] -----
// grid (8, 96): 32-n tile x one p. block 256.
__global__ __launch_bounds__(256) void k_reduce_trend(const float* __restrict__ part,
                                                      const float* __restrict__ bt,
                                                      float* __restrict__ out0) {
    int nt = blockIdx.x, p = blockIdx.y, tid = threadIdx.x;
    __shared__ float t[32][65];
    int n0 = nt * 32;
    for (int idx = tid; idx < 2048; idx += 256) {
        int i = idx >> 6, j = idx & 63;
        size_t o = (size_t)(n0 + i) * PB_ + p * 64 + j;
        t[i][j] = part[o] + part[(size_t)N_ * PB_ + o];
    }
    __syncthreads();
    for (int idx = tid; idx < 2048; idx += 256) {
        int bb = idx >> 5, nl = idx & 31;
        out0[((size_t)bb * P_ + p) * N_ + n0 + nl] = t[nl][bb] + bt[(size_t)p * N_ + n0 + nl];
    }
}

// ---------------- Kernel 5: season attention scores ----------------
__global__ __launch_bounds__(256) void k_season_scores(float* ws) {
    int b = blockIdx.x, kt = blockIdx.y, tid = threadIdx.x;
    const float* EN = ws + OFF_EN + (size_t)b * P_ * D_;
    const float* ET = ws + OFF_ET + (size_t)b * L_ * D_;
    float* W = ws + OFF_WSE + (size_t)b * P_ * L_;
    __shared__ float Al[96][68];
    __shared__ float Bl[64][68];
    for (int idx = tid; idx < 96 * 16; idx += 256) {
        int q = idx >> 4, d4 = (idx & 15) * 4;
        *(float4*)&Al[q][d4] = *(const float4*)&EN[q * 64 + d4];
    }
    int k0 = kt * 64;
    for (int idx = tid; idx < 64 * 16; idx += 256) {
        int kk = idx >> 4, d4 = (idx & 15) * 4;
        float4 v = (k0 + kk < L_) ? *(const float4*)&ET[(size_t)(k0 + kk) * D_ + d4]
                                  : make_float4(0.f, 0.f, 0.f, 0.f);
        *(float4*)&Bl[kk][d4] = v;
    }
    __syncthreads();
    int qt = tid >> 4, ktl = tid & 15;
    float acc[6][4] = {};
    for (int d = 0; d < 64; d += 4) {
        float4 av[6], bv[4];
#pragma unroll
        for (int j = 0; j < 6; ++j) av[j] = *(const float4*)&Al[qt + 16 * j][d];
#pragma unroll
        for (int i = 0; i < 4; ++i) bv[i] = *(const float4*)&Bl[ktl + 16 * i][d];
#pragma unroll
        for (int j = 0; j < 6; ++j)
#pragma unroll
            for (int i = 0; i < 4; ++i)
                acc[j][i] += av[j].x * bv[i].x + av[j].y * bv[i].y +
                             av[j].z * bv[i].z + av[j].w * bv[i].w;
    }
#pragma unroll
    for (int j = 0; j < 6; ++j) {
        int q = qt + 16 * j;
#pragma unroll
        for (int i = 0; i < 4; ++i) {
            int k = k0 + ktl + 16 * i;
            if (k < L_) W[(size_t)q * L_ + k] = acc[j][i] * 0.125f;
        }
    }
}

// ------- Kernel 6: one-wave-per-row softmax over L_ (raw -> normalized) ----
__global__ __launch_bounds__(64) void k_softmax_rows(float* __restrict__ base_g) {
    float* base = base_g + (size_t)blockIdx.x * L_;
    int lane = threadIdx.x;
    float v[8];
    float m = -FLT_MAX;
#pragma unroll
    for (int i = 0; i < 8; ++i) {
        int idx = i * 64 + lane;
        v[i] = (idx < L_) ? base[idx] : -FLT_MAX;
        m = fmaxf(m, v[i]);
    }
    for (int off = 32; off; off >>= 1) m = fmaxf(m, __shfl_xor(m, off));
    float s = 0.f;
#pragma unroll
    for (int i = 0; i < 8; ++i) {
        float e = expf(v[i] - m);
        v[i] = e; s += e;
    }
    for (int off = 32; off; off >>= 1) s += __shfl_xor(s, off);
    float inv = 1.f / s;
#pragma unroll
    for (int i = 0; i < 8; ++i) {
        int idx = i * 64 + lane;
        if (idx < L_) base[idx] = v[i] * inv;
    }
}

// ------- Kernel 7: mid masked raw scores, grid (B, 8 k-tiles) ----------
__global__ __launch_bounds__(256) void k_mid_scores(float* ws) {
    int b = blockIdx.x, kt = blockIdx.y, tid = threadIdx.x;
    const float* ET = ws + OFF_ET + (size_t)b * L_ * D_;
    float* WM = ws + OFF_WM + (size_t)b * MID_ * L_;
    __shared__ float qv[7][68];
    __shared__ float Bl[64 * 65];
    for (int idx = tid; idx < 7 * 16; idx += 256) {
        int q = idx >> 4, d4 = (idx & 15) * 4;
        *(float4*)&qv[q][d4] = *(const float4*)&ET[(size_t)(L_ - MID_ + q) * D_ + d4];
    }
    int k0 = kt * 64;
    for (int idx = tid; idx < 64 * 16; idx += 256) {
        int kk = idx >> 4, d4 = (idx & 15) * 4;
        float4 v = (k0 + kk < L_) ? *(const float4*)&ET[(size_t)(k0 + kk) * D_ + d4]
                                  : make_float4(0.f, 0.f, 0.f, 0.f);
        Bl[kk * 65 + d4 + 0] = v.x;
        Bl[kk * 65 + d4 + 1] = v.y;
        Bl[kk * 65 + d4 + 2] = v.z;
        Bl[kk * 65 + d4 + 3] = v.w;
    }
    __syncthreads();
    int klane = tid & 63, qs = tid >> 6;        // qs 0..3 (wave-uniform)
    int q0 = qs, q1 = qs + 4;                   // q1==7 invalid for qs==3
    float a0 = 0.f, a1 = 0.f;
    for (int d = 0; d < 64; ++d) {
        float e = Bl[klane * 65 + d];
        a0 += e * qv[q0][d];
        if (q1 < 7) a1 += e * qv[q1][d];
    }
    int k = k0 + klane;
    if (k < L_) {
        WM[(size_t)q0 * L_ + k] = (k < L_ - MID_ + q0) ? a0 * 0.125f : -FLT_MAX;
        if (q1 < 7)
            WM[(size_t)q1 * L_ + k] = (k < L_ - MID_ + q1) ? a1 * 0.125f : -FLT_MAX;
    }
}

// ------- Kernel 8: season PV, k-split x2, atomicAdd into out0 -------------
// grid (B, 4 n-tiles, 2 k-splits), block 256.
__global__ __launch_bounds__(256) void k_season_pv(const float* __restrict__ ws_c,
                                                   float* __restrict__ out0) {
    int b = blockIdx.x, nt = blockIdx.y, ks = blockIdx.z, tid = threadIdx.x;
    const float* Wb = ws_c + OFF_WSE + (size_t)b * P_ * L_;
    const float* Xs = ws_c + OFF_XS + (size_t)b * L_ * N_;
    __shared__ float Wl[96][36];
    __shared__ float Xl[32][68];
    int qt = tid >> 4, ntl = tid & 15;
    float acc[6][4] = {};
    int kb = ks * 244, ke = kb + 244;
    for (int k0 = kb; k0 < ke; k0 += 32) {
        int cur = ke - k0; if (cur > 32) cur = 32;
        for (int idx = tid; idx < 96 * 8; idx += 256) {
            int q = idx >> 3, l4 = (idx & 7) * 4;
            float4 v = (l4 < cur) ? *(const float4*)&Wb[(size_t)q * L_ + k0 + l4]
                                  : make_float4(0.f, 0.f, 0.f, 0.f);
            *(float4*)&Wl[q][l4] = v;
        }
        for (int idx = tid; idx < 32 * 16; idx += 256) {
            int kc = idx >> 4, n4 = (idx & 15) * 4;
            float4 v = (kc < cur) ? *(const float4*)&Xs[(size_t)(k0 + kc) * N_ + nt * 64 + n4]
                                  : make_float4(0.f, 0.f, 0.f, 0.f);
            *(float4*)&Xl[kc][n4] = v;
        }
        __syncthreads();
        for (int kc = 0; kc < 32; kc += 4) {
            float4 wv[6];
#pragma unroll
            for (int j = 0; j < 6; ++j) wv[j] = *(const float4*)&Wl[qt + 16 * j][kc];
#pragma unroll
            for (int t = 0; t < 4; ++t) {
                float4 xv = *(const float4*)&Xl[kc + t][ntl * 4];
#pragma unroll
                for (int j = 0; j < 6; ++j) {
                    float w = (t == 0) ? wv[j].x : (t == 1) ? wv[j].y : (t == 2) ? wv[j].z : wv[j].w;
                    acc[j][0] += w * xv.x;
                    acc[j][1] += w * xv.y;
                    acc[j][2] += w * xv.z;
                    acc[j][3] += w * xv.w;
                }
            }
        }
        __syncthreads();
    }
#pragma unroll
    for (int j = 0; j < 6; ++j) {
        int q = qt + 16 * j;
        float* base = &out0[((size_t)b * P_ + q) * N_ + nt * 64 + ntl * 4];
        atomicAdd(base + 0, acc[j][0]);
        atomicAdd(base + 1, acc[j][1]);
        atomicAdd(base + 2, acc[j][2]);
        atomicAdd(base + 3, acc[j][3]);
    }
}

// ------- Kernel 9: mid PV -> out1, 8-way k-slices in one block -------------
// grid (B, 4 n-tiles), block 512 (= 64 n x 8 k-slices of 61)
__global__ __launch_bounds__(512) void k_mid_pv(const float* __restrict__ ws_c,
                                                float* __restrict__ out1) {
    int b = blockIdx.x, nt = blockIdx.y, tid = threadIdx.x;
    int nl = tid & 63, ks = tid >> 6;   // ks 0..7
    const float* Xs = ws_c + OFF_XS + (size_t)b * L_ * N_;
    const float* WM = ws_c + OFF_WM + (size_t)b * MID_ * L_;
    __shared__ float wl[7 * L_];
    __shared__ float part[8][7][64];
    for (int idx = tid; idx < 7 * L_; idx += 512) wl[idx] = WM[idx];
    __syncthreads();
    float acc[7] = {};
    int kbeg = ks * 61, kend = kbeg + 61;
    for (int k = kbeg; k < kend; ++k) {
        float xv = Xs[(size_t)k * N_ + nt * 64 + nl];
#pragma unroll
        for (int q = 0; q < 7; ++q) acc[q] += wl[q * L_ + k] * xv;
    }
#pragma unroll
    for (int q = 0; q < 7; ++q) part[ks][q][nl] = acc[q];
    __syncthreads();
    if (ks == 0) {
#pragma unroll
        for (int q = 0; q < 7; ++q) {
            float v = 0.f;
#pragma unroll
            for (int s = 0; s < 8; ++s) v += part[s][q][nl];
            out1[((size_t)b * MID_ + q) * N_ + nt * 64 + nl] = v;
        }
    }
}

extern "C" void kernel_launch(void* const* d_in, const int* in_sizes, int n_in,
                              void* d_out, int out_size, void* d_ws, size_t ws_size,
                              hipStream_t stream) {
    (void)in_sizes; (void)n_in; (void)out_size; (void)ws_size;
    const float* X  = (const float*)d_in[0];
    const float* T  = (const float*)d_in[1];
    const float* Wt = (const float*)d_in[2];
    const float* bt = (const float*)d_in[3];
    const float* w0 = (const float*)d_in[4];
    const float* b0 = (const float*)d_in[5];
    const float* Wp = (const float*)d_in[6];
    const float* Bp = (const float*)d_in[7];
    float* out = (float*)d_out;
    float* ws  = (float*)d_ws;
    float* out1 = out + (size_t)B_ * P_ * N_;

    hipLaunchKernelGGL(k_trend, dim3(B_, 8), dim3(256), 0, stream, X, ws);
    hipLaunchKernelGGL(k_embed, dim3((B_ * (L_ + P_) * D_) / 256), dim3(256), 0, stream,
                       T, w0, b0, Wp, Bp, ws);
    hipLaunchKernelGGL(k_trend_gemm, dim3(N_, 2), dim3(256), 0, stream, Wt, ws, ws + OFF_PART);
    hipLaunchKernelGGL(k_reduce_trend, dim3(8, 96), dim3(256), 0, stream, ws + OFF_PART, bt, out);
    hipLaunchKernelGGL(k_season_scores, dim3(B_, 8), dim3(256), 0, stream, ws);
    hipLaunchKernelGGL(k_softmax_rows, dim3(B_ * P_), dim3(64), 0, stream, ws + OFF_WSE);
    hipLaunchKernelGGL(k_mid_scores, dim3(B_, 8), dim3(256), 0, stream, ws);
    hipLaunchKernelGGL(k_softmax_rows, dim3(B_ * MID_), dim3(64), 0, stream, ws + OFF_WM);
    hipLaunchKernelGGL(k_season_pv, dim3(B_, 4, 2), dim3(256), 0, stream, ws, out);
    hipLaunchKernelGGL(k_mid_pv, dim3(B_, 4), dim3(512), 0, stream, ws, out1);
}

// Round 3
// 310.742 us; speedup vs baseline: 1.8124x; 1.1853x over previous
//
#include <hip/hip_runtime.h>
#include <math.h>
#include <float.h>

#define B_ 64
#define S_ 512
#define N_ 256
#define P_ 96
#define D_ 64
#define WIN_ 24
#define L_ 488   // S_ - WIN_
#define MID_ 7
#define PB_ (P_*B_)   // 6144

// workspace layout (in floats)
#define OFF_XS   ((size_t)0)                        // season [B][L][N]
#define OFF_TRT  (OFF_XS  + (size_t)B_*L_*N_)       // trend^T [N][B][L]
#define OFF_ET   (OFF_TRT + (size_t)N_*B_*L_)       // embed_t [B][L][D]
#define OFF_EN   (OFF_ET  + (size_t)B_*L_*D_)       // embed_next [B][P][D]
#define OFF_WSE  (OFF_EN  + (size_t)B_*P_*D_)       // season weights [B][P][L]
#define OFF_WM   (OFF_WSE + (size_t)B_*P_*L_)       // mid weights [B][MID][L]
// trend-GEMM partials alias WSE+WM (2*N*PB = 3.15M floats <= 3.22M), consumed
// by k_reduce_trend BEFORE season/mid scores write WSE/WM.
#define OFF_PART OFF_WSE

// ---------------- Kernel 1: rolling-mean trend + season ----------------
// grid (B, 8), block 256 (thread = n). LDS-transposed trT writes.
__global__ __launch_bounds__(256) void k_trend(const float* __restrict__ X,
                                               float* __restrict__ ws) {
    int b = blockIdx.x, tile = blockIdx.y, n = threadIdx.x;
    __shared__ float tr_tile[256][61];   // stride 61 (odd): 2-way bank alias = free
    float* Xs  = ws + OFF_XS;
    float* trT = ws + OFF_TRT;
    const float* Xb = X + (size_t)b * S_ * N_ + n;
    int s1 = WIN_ + tile * 61;
    float wsum = 0.f;
    for (int s = s1 - WIN_; s < s1; ++s) wsum += Xb[(size_t)s * N_];
    for (int i = 0; i < 61; ++i) {
        int s = s1 + i, l = s - WIN_;
        float xv = Xb[(size_t)s * N_];
        wsum += xv - Xb[(size_t)(s - WIN_) * N_];
        float tr = wsum * (1.f / WIN_);
        Xs[((size_t)b * L_ + l) * N_ + n] = xv - tr;   // coalesced
        tr_tile[n][i] = tr;
    }
    __syncthreads();
    int lane = threadIdx.x & 63, row4 = threadIdx.x >> 6;
    int l0 = tile * 61;
    for (int r = row4; r < 256; r += 4) {
        if (lane < 61)
            trT[(size_t)r * (B_ * L_) + (size_t)b * L_ + l0 + lane] = tr_tile[r][lane];
    }
}

// ---------------- Kernel 2: time2vec embeds ----------------
__global__ __launch_bounds__(256) void k_embed(const float* __restrict__ T,
                                               const float* __restrict__ w0,
                                               const float* __restrict__ b0,
                                               const float* __restrict__ Wp,
                                               const float* __restrict__ Bp,
                                               float* __restrict__ ws) {
    int idx = blockIdx.x * 256 + threadIdx.x;
    int d = idx & 63;
    int rest = idx >> 6;
    int pos = rest % (L_ + P_);
    int b = rest / (L_ + P_);
    float t;
    float* dst;
    if (pos < L_) {
        t = T[(size_t)b * S_ + WIN_ + pos];
        dst = ws + OFF_ET + ((size_t)b * L_ + pos) * D_ + d;
    } else {
        int p = pos - L_;
        t = T[(size_t)b * S_ + (S_ - 1)] + (float)(p + 1);
        dst = ws + OFF_EN + ((size_t)b * P_ + p) * D_ + d;
    }
    float v = (d == 0) ? (t * w0[0] + b0[0]) : sinf(t * Wp[d - 1] + Bp[d - 1]);
    *dst = v;
}

// ------- Kernel 3: trend GEMM, k-split x2, register-prefetch pipelined -----
// grid (N_, 2), block 256. partial[ks][n][p*64+bb]
__global__ __launch_bounds__(256) void k_trend_gemm(const float* __restrict__ Wt_g,
                                                    const float* __restrict__ ws_c,
                                                    float* __restrict__ part) {
    int n = blockIdx.x, ks = blockIdx.y, tid = threadIdx.x;
    __shared__ float smem[6144];
    float* Wl = smem;          // [96][36]
    float* Bl = smem + 3456;   // [64][36]
    const float* trT = ws_c + OFF_TRT + (size_t)n * B_ * L_;
    const float* Wn  = Wt_g + (size_t)n * P_ * L_;
    int pt = tid >> 4, btl = tid & 15;
    float acc[6][4] = {};
    float4 wr[3], br[2];

    auto fetch = [&](int l0, int ke) {
        int cur = ke - l0;
#pragma unroll
        for (int t = 0; t < 3; ++t) {
            int idx = tid + t * 256;
            int p = idx >> 3, l4 = (idx & 7) * 4;
            wr[t] = (l4 < cur) ? *(const float4*)&Wn[(size_t)p * L_ + l0 + l4]
                               : make_float4(0.f, 0.f, 0.f, 0.f);
        }
#pragma unroll
        for (int t = 0; t < 2; ++t) {
            int idx = tid + t * 256;
            int bb = idx >> 3, l4 = (idx & 7) * 4;
            br[t] = (l4 < cur) ? *(const float4*)&trT[(size_t)bb * L_ + l0 + l4]
                               : make_float4(0.f, 0.f, 0.f, 0.f);
        }
    };
    auto stage = [&]() {
#pragma unroll
        for (int t = 0; t < 3; ++t) {
            int idx = tid + t * 256;
            *(float4*)&Wl[(idx >> 3) * 36 + (idx & 7) * 4] = wr[t];
        }
#pragma unroll
        for (int t = 0; t < 2; ++t) {
            int idx = tid + t * 256;
            *(float4*)&Bl[(idx >> 3) * 36 + (idx & 7) * 4] = br[t];
        }
    };
    auto compute = [&]() {
        for (int lc = 0; lc < 32; lc += 4) {
            float4 wv[6], bv[4];
#pragma unroll
            for (int j = 0; j < 6; ++j) wv[j] = *(const float4*)&Wl[(pt + 16 * j) * 36 + lc];
#pragma unroll
            for (int i = 0; i < 4; ++i) bv[i] = *(const float4*)&Bl[(btl + 16 * i) * 36 + lc];
#pragma unroll
            for (int j = 0; j < 6; ++j)
#pragma unroll
                for (int i = 0; i < 4; ++i)
                    acc[j][i] += wv[j].x * bv[i].x + wv[j].y * bv[i].y +
                                 wv[j].z * bv[i].z + wv[j].w * bv[i].w;
        }
    };

    int kb = ks * 244, ke = kb + 244;          // chunks: 7x32 + 20 (20 % 4 == 0)
    fetch(kb, ke);
    stage();
    for (int l0 = kb + 32; l0 < ke; l0 += 32) {
        fetch(l0, ke);       // global loads in flight during compute
        __syncthreads();
        compute();
        __syncthreads();
        stage();             // waits on vmcnt, writes LDS
    }
    __syncthreads();
    compute();

    // stage C into LDS, write coalesced
    float* Cst = smem;
    __syncthreads();
#pragma unroll
    for (int j = 0; j < 6; ++j)
#pragma unroll
        for (int i = 0; i < 4; ++i)
            Cst[(pt + 16 * j) * 64 + (btl + 16 * i)] = acc[j][i];
    __syncthreads();
    float4* dst = (float4*)(part + ((size_t)ks * N_ + n) * PB_);
    const float4* src = (const float4*)Cst;
    for (int i = tid; i < PB_ / 4; i += 256) dst[i] = src[i];
}

// ------- Kernel 4: reduce partials + bias, transpose to out0 [b][p][n] -----
__global__ __launch_bounds__(256) void k_reduce_trend(const float* __restrict__ part,
                                                      const float* __restrict__ bt,
                                                      float* __restrict__ out0) {
    int nt = blockIdx.x, p = blockIdx.y, tid = threadIdx.x;
    __shared__ float t[32][65];
    int n0 = nt * 32;
    for (int idx = tid; idx < 2048; idx += 256) {
        int i = idx >> 6, j = idx & 63;
        size_t o = (size_t)(n0 + i) * PB_ + p * 64 + j;
        t[i][j] = part[o] + part[(size_t)N_ * PB_ + o];
    }
    __syncthreads();
    for (int idx = tid; idx < 2048; idx += 256) {
        int bb = idx >> 5, nl = idx & 31;
        out0[((size_t)bb * P_ + p) * N_ + n0 + nl] = t[nl][bb] + bt[(size_t)p * N_ + n0 + nl];
    }
}

// ---------------- Kernel 5: season attention scores ----------------
__global__ __launch_bounds__(256) void k_season_scores(float* ws) {
    int b = blockIdx.x, kt = blockIdx.y, tid = threadIdx.x;
    const float* EN = ws + OFF_EN + (size_t)b * P_ * D_;
    const float* ET = ws + OFF_ET + (size_t)b * L_ * D_;
    float* W = ws + OFF_WSE + (size_t)b * P_ * L_;
    __shared__ float Al[96][68];
    __shared__ float Bl[64][68];
    for (int idx = tid; idx < 96 * 16; idx += 256) {
        int q = idx >> 4, d4 = (idx & 15) * 4;
        *(float4*)&Al[q][d4] = *(const float4*)&EN[q * 64 + d4];
    }
    int k0 = kt * 64;
    for (int idx = tid; idx < 64 * 16; idx += 256) {
        int kk = idx >> 4, d4 = (idx & 15) * 4;
        float4 v = (k0 + kk < L_) ? *(const float4*)&ET[(size_t)(k0 + kk) * D_ + d4]
                                  : make_float4(0.f, 0.f, 0.f, 0.f);
        *(float4*)&Bl[kk][d4] = v;
    }
    __syncthreads();
    int qt = tid >> 4, ktl = tid & 15;
    float acc[6][4] = {};
    for (int d = 0; d < 64; d += 4) {
        float4 av[6], bv[4];
#pragma unroll
        for (int j = 0; j < 6; ++j) av[j] = *(const float4*)&Al[qt + 16 * j][d];
#pragma unroll
        for (int i = 0; i < 4; ++i) bv[i] = *(const float4*)&Bl[ktl + 16 * i][d];
#pragma unroll
        for (int j = 0; j < 6; ++j)
#pragma unroll
            for (int i = 0; i < 4; ++i)
                acc[j][i] += av[j].x * bv[i].x + av[j].y * bv[i].y +
                             av[j].z * bv[i].z + av[j].w * bv[i].w;
    }
#pragma unroll
    for (int j = 0; j < 6; ++j) {
        int q = qt + 16 * j;
#pragma unroll
        for (int i = 0; i < 4; ++i) {
            int k = k0 + ktl + 16 * i;
            if (k < L_) W[(size_t)q * L_ + k] = acc[j][i] * 0.125f;
        }
    }
}

// ------- Kernel 6: one-wave-per-row softmax over L_ ----
__global__ __launch_bounds__(64) void k_softmax_rows(float* __restrict__ base_g) {
    float* base = base_g + (size_t)blockIdx.x * L_;
    int lane = threadIdx.x;
    float v[8];
    float m = -FLT_MAX;
#pragma unroll
    for (int i = 0; i < 8; ++i) {
        int idx = i * 64 + lane;
        v[i] = (idx < L_) ? base[idx] : -FLT_MAX;
        m = fmaxf(m, v[i]);
    }
    for (int off = 32; off; off >>= 1) m = fmaxf(m, __shfl_xor(m, off));
    float s = 0.f;
#pragma unroll
    for (int i = 0; i < 8; ++i) {
        float e = expf(v[i] - m);
        v[i] = e; s += e;
    }
    for (int off = 32; off; off >>= 1) s += __shfl_xor(s, off);
    float inv = 1.f / s;
#pragma unroll
    for (int i = 0; i < 8; ++i) {
        int idx = i * 64 + lane;
        if (idx < L_) base[idx] = v[i] * inv;
    }
}

// ------- Kernel 7: mid masked raw scores, grid (B, 8 k-tiles) ----------
__global__ __launch_bounds__(256) void k_mid_scores(float* ws) {
    int b = blockIdx.x, kt = blockIdx.y, tid = threadIdx.x;
    const float* ET = ws + OFF_ET + (size_t)b * L_ * D_;
    float* WM = ws + OFF_WM + (size_t)b * MID_ * L_;
    __shared__ float qv[7][68];
    __shared__ float Bl[64 * 65];
    for (int idx = tid; idx < 7 * 16; idx += 256) {
        int q = idx >> 4, d4 = (idx & 15) * 4;
        *(float4*)&qv[q][d4] = *(const float4*)&ET[(size_t)(L_ - MID_ + q) * D_ + d4];
    }
    int k0 = kt * 64;
    for (int idx = tid; idx < 64 * 16; idx += 256) {
        int kk = idx >> 4, d4 = (idx & 15) * 4;
        float4 v = (k0 + kk < L_) ? *(const float4*)&ET[(size_t)(k0 + kk) * D_ + d4]
                                  : make_float4(0.f, 0.f, 0.f, 0.f);
        Bl[kk * 65 + d4 + 0] = v.x;
        Bl[kk * 65 + d4 + 1] = v.y;
        Bl[kk * 65 + d4 + 2] = v.z;
        Bl[kk * 65 + d4 + 3] = v.w;
    }
    __syncthreads();
    int klane = tid & 63, qs = tid >> 6;
    int q0 = qs, q1 = qs + 4;
    float a0 = 0.f, a1 = 0.f;
    for (int d = 0; d < 64; ++d) {
        float e = Bl[klane * 65 + d];
        a0 += e * qv[q0][d];
        if (q1 < 7) a1 += e * qv[q1][d];
    }
    int k = k0 + klane;
    if (k < L_) {
        WM[(size_t)q0 * L_ + k] = (k < L_ - MID_ + q0) ? a0 * 0.125f : -FLT_MAX;
        if (q1 < 7)
            WM[(size_t)q1 * L_ + k] = (k < L_ - MID_ + q1) ? a1 * 0.125f : -FLT_MAX;
    }
}

// ------- Kernel 8: season PV, k-split x4, prefetch, atomicAdd into out0 ----
// grid (B, 4 n-tiles, 4 k-splits), block 256. splits 120/120/120/128.
__global__ __launch_bounds__(256) void k_season_pv(const float* __restrict__ ws_c,
                                                   float* __restrict__ out0) {
    int b = blockIdx.x, nt = blockIdx.y, ks = blockIdx.z, tid = threadIdx.x;
    const float* Wb = ws_c + OFF_WSE + (size_t)b * P_ * L_;
    const float* Xs = ws_c + OFF_XS + (size_t)b * L_ * N_;
    __shared__ float Wl[96][36];
    __shared__ float Xl[32][68];
    int qt = tid >> 4, ntl = tid & 15;
    float acc[6][4] = {};
    float4 wr[3], xr[2];

    auto fetch = [&](int k0, int ke) {
        int cur = ke - k0;
#pragma unroll
        for (int t = 0; t < 3; ++t) {
            int idx = tid + t * 256;
            int q = idx >> 3, l4 = (idx & 7) * 4;
            wr[t] = (l4 < cur) ? *(const float4*)&Wb[(size_t)q * L_ + k0 + l4]
                               : make_float4(0.f, 0.f, 0.f, 0.f);
        }
#pragma unroll
        for (int t = 0; t < 2; ++t) {
            int idx = tid + t * 256;
            int kc = idx >> 4, n4 = (idx & 15) * 4;
            xr[t] = (kc < cur) ? *(const float4*)&Xs[(size_t)(k0 + kc) * N_ + nt * 64 + n4]
                               : make_float4(0.f, 0.f, 0.f, 0.f);
        }
    };
    auto stage = [&]() {
#pragma unroll
        for (int t = 0; t < 3; ++t) {
            int idx = tid + t * 256;
            *(float4*)&Wl[idx >> 3][(idx & 7) * 4] = wr[t];
        }
#pragma unroll
        for (int t = 0; t < 2; ++t) {
            int idx = tid + t * 256;
            *(float4*)&Xl[idx >> 4][(idx & 15) * 4] = xr[t];
        }
    };
    auto compute = [&]() {
        for (int kc = 0; kc < 32; kc += 4) {
            float4 wv[6];
#pragma unroll
            for (int j = 0; j < 6; ++j) wv[j] = *(const float4*)&Wl[qt + 16 * j][kc];
#pragma unroll
            for (int t = 0; t < 4; ++t) {
                float4 xv = *(const float4*)&Xl[kc + t][ntl * 4];
#pragma unroll
                for (int j = 0; j < 6; ++j) {
                    float w = (t == 0) ? wv[j].x : (t == 1) ? wv[j].y : (t == 2) ? wv[j].z : wv[j].w;
                    acc[j][0] += w * xv.x;
                    acc[j][1] += w * xv.y;
                    acc[j][2] += w * xv.z;
                    acc[j][3] += w * xv.w;
                }
            }
        }
    };

    int kb = ks * 120, ke = (ks == 3) ? L_ : kb + 120;  // 120=3x32+24, 128=4x32
    fetch(kb, ke);
    stage();
    for (int k0 = kb + 32; k0 < ke; k0 += 32) {
        fetch(k0, ke);
        __syncthreads();
        compute();
        __syncthreads();
        stage();
    }
    __syncthreads();
    compute();

#pragma unroll
    for (int j = 0; j < 6; ++j) {
        int q = qt + 16 * j;
        float* base = &out0[((size_t)b * P_ + q) * N_ + nt * 64 + ntl * 4];
        atomicAdd(base + 0, acc[j][0]);
        atomicAdd(base + 1, acc[j][1]);
        atomicAdd(base + 2, acc[j][2]);
        atomicAdd(base + 3, acc[j][3]);
    }
}

// ------- Kernel 9: mid PV -> out1, 8-way k-slices in one block -------------
__global__ __launch_bounds__(512) void k_mid_pv(const float* __restrict__ ws_c,
                                                float* __restrict__ out1) {
    int b = blockIdx.x, nt = blockIdx.y, tid = threadIdx.x;
    int nl = tid & 63, ks = tid >> 6;
    const float* Xs = ws_c + OFF_XS + (size_t)b * L_ * N_;
    const float* WM = ws_c + OFF_WM + (size_t)b * MID_ * L_;
    __shared__ float wl[7 * L_];
    __shared__ float part[8][7][64];
    for (int idx = tid; idx < 7 * L_; idx += 512) wl[idx] = WM[idx];
    __syncthreads();
    float acc[7] = {};
    int kbeg = ks * 61, kend = kbeg + 61;
    for (int k = kbeg; k < kend; ++k) {
        float xv = Xs[(size_t)k * N_ + nt * 64 + nl];
#pragma unroll
        for (int q = 0; q < 7; ++q) acc[q] += wl[q * L_ + k] * xv;
    }
#pragma unroll
    for (int q = 0; q < 7; ++q) part[ks][q][nl] = acc[q];
    __syncthreads();
    if (ks == 0) {
#pragma unroll
        for (int q = 0; q < 7; ++q) {
            float v = 0.f;
#pragma unroll
            for (int s = 0; s < 8; ++s) v += part[s][q][nl];
            out1[((size_t)b * MID_ + q) * N_ + nt * 64 + nl] = v;
        }
    }
}

extern "C" void kernel_launch(void* const* d_in, const int* in_sizes, int n_in,
                              void* d_out, int out_size, void* d_ws, size_t ws_size,
                              hipStream_t stream) {
    (void)in_sizes; (void)n_in; (void)out_size; (void)ws_size;
    const float* X  = (const float*)d_in[0];
    const float* T  = (const float*)d_in[1];
    const float* Wt = (const float*)d_in[2];
    const float* bt = (const float*)d_in[3];
    const float* w0 = (const float*)d_in[4];
    const float* b0 = (const float*)d_in[5];
    const float* Wp = (const float*)d_in[6];
    const float* Bp = (const float*)d_in[7];
    float* out = (float*)d_out;
    float* ws  = (float*)d_ws;
    float* out1 = out + (size_t)B_ * P_ * N_;

    hipLaunchKernelGGL(k_trend, dim3(B_, 8), dim3(256), 0, stream, X, ws);
    hipLaunchKernelGGL(k_embed, dim3((B_ * (L_ + P_) * D_) / 256), dim3(256), 0, stream,
                       T, w0, b0, Wp, Bp, ws);
    hipLaunchKernelGGL(k_trend_gemm, dim3(N_, 2), dim3(256), 0, stream, Wt, ws, ws + OFF_PART);
    hipLaunchKernelGGL(k_reduce_trend, dim3(8, 96), dim3(256), 0, stream, ws + OFF_PART, bt, out);
    hipLaunchKernelGGL(k_season_scores, dim3(B_, 8), dim3(256), 0, stream, ws);
    hipLaunchKernelGGL(k_softmax_rows, dim3(B_ * P_), dim3(64), 0, stream, ws + OFF_WSE);
    hipLaunchKernelGGL(k_mid_scores, dim3(B_, 8), dim3(256), 0, stream, ws);
    hipLaunchKernelGGL(k_softmax_rows, dim3(B_ * MID_), dim3(64), 0, stream, ws + OFF_WM);
    hipLaunchKernelGGL(k_season_pv, dim3(B_, 4, 4), dim3(256), 0, stream, ws, out);
    hipLaunchKernelGGL(k_mid_pv, dim3(B_, 4), dim3(512), 0, stream, ws, out1);
}

// Round 4
// 287.830 us; speedup vs baseline: 1.9567x; 1.0796x over previous
//
#include <hip/hip_runtime.h>
#include <math.h>
#include <float.h>

#define B_ 64
#define S_ 512
#define N_ 256
#define P_ 96
#define D_ 64
#define WIN_ 24
#define L_ 488   // S_ - WIN_
#define MID_ 7
#define PB_ (P_*B_)   // 6144

// workspace layout (in floats)
#define OFF_XS   ((size_t)0)                        // season [B][L][N]
#define OFF_TRT  (OFF_XS  + (size_t)B_*L_*N_)       // trend^T [N][B][L]
#define OFF_ET   (OFF_TRT + (size_t)N_*B_*L_)       // embed_t [B][L][D]
#define OFF_EN   (OFF_ET  + (size_t)B_*L_*D_)       // embed_next [B][P][D]
#define OFF_WSE  (OFF_EN  + (size_t)B_*P_*D_)       // season weights [B][P][L]
#define OFF_WM   (OFF_WSE + (size_t)B_*P_*L_)       // mid weights [B][MID][L]
// trend-GEMM partials alias WSE (N*PB = 1.57M floats), consumed by
// k_reduce_trend BEFORE season scores write WSE.
#define OFF_PART OFF_WSE

// ---------------- Kernel 1: rolling-mean trend + season ----------------
// grid (B, 8), block 256 (thread = n). LDS-transposed trT writes.
__global__ __launch_bounds__(256) void k_trend(const float* __restrict__ X,
                                               float* __restrict__ ws) {
    int b = blockIdx.x, tile = blockIdx.y, n = threadIdx.x;
    __shared__ float tr_tile[256][61];   // stride 61 (odd): 2-way bank alias = free
    float* Xs  = ws + OFF_XS;
    float* trT = ws + OFF_TRT;
    const float* Xb = X + (size_t)b * S_ * N_ + n;
    int s1 = WIN_ + tile * 61;
    float wsum = 0.f;
    for (int s = s1 - WIN_; s < s1; ++s) wsum += Xb[(size_t)s * N_];
    for (int i = 0; i < 61; ++i) {
        int s = s1 + i, l = s - WIN_;
        float xv = Xb[(size_t)s * N_];
        wsum += xv - Xb[(size_t)(s - WIN_) * N_];
        float tr = wsum * (1.f / WIN_);
        Xs[((size_t)b * L_ + l) * N_ + n] = xv - tr;   // coalesced
        tr_tile[n][i] = tr;
    }
    __syncthreads();
    int lane = threadIdx.x & 63, row4 = threadIdx.x >> 6;
    int l0 = tile * 61;
    for (int r = row4; r < 256; r += 4) {
        if (lane < 61)
            trT[(size_t)r * (B_ * L_) + (size_t)b * L_ + l0 + lane] = tr_tile[r][lane];
    }
}

// ---------------- Kernel 2: time2vec embeds ----------------
__global__ __launch_bounds__(256) void k_embed(const float* __restrict__ T,
                                               const float* __restrict__ w0,
                                               const float* __restrict__ b0,
                                               const float* __restrict__ Wp,
                                               const float* __restrict__ Bp,
                                               float* __restrict__ ws) {
    int idx = blockIdx.x * 256 + threadIdx.x;
    int d = idx & 63;
    int rest = idx >> 6;
    int pos = rest % (L_ + P_);
    int b = rest / (L_ + P_);
    float t;
    float* dst;
    if (pos < L_) {
        t = T[(size_t)b * S_ + WIN_ + pos];
        dst = ws + OFF_ET + ((size_t)b * L_ + pos) * D_ + d;
    } else {
        int p = pos - L_;
        t = T[(size_t)b * S_ + (S_ - 1)] + (float)(p + 1);
        dst = ws + OFF_EN + ((size_t)b * P_ + p) * D_ + d;
    }
    float v = (d == 0) ? (t * w0[0] + b0[0]) : sinf(t * Wp[d - 1] + Bp[d - 1]);
    *dst = v;
}

// ------- Kernel 3: trend GEMM, p-split x2 (no reduction), pipelined --------
// grid (N_, 2), block 256. Writes disjoint partial[n][p][b], p-half per block.
__global__ __launch_bounds__(256) void k_trend_gemm(const float* __restrict__ Wt_g,
                                                    const float* __restrict__ ws_c,
                                                    float* __restrict__ part) {
    int n = blockIdx.x, ptb = blockIdx.y, tid = threadIdx.x;
    __shared__ float smem[4032];         // Wl[48][36] + Bl[64][36]
    float* Wl = smem;
    float* Bl = smem + 1728;
    const float* trT = ws_c + OFF_TRT + (size_t)n * B_ * L_;
    const float* Wn  = Wt_g + ((size_t)n * P_ + (size_t)ptb * 48) * L_;
    int pt = tid >> 4, btl = tid & 15;
    float acc[3][4] = {};
    float4 wr[2], br[2];

    auto fetch = [&](int l0) {
        int cur = L_ - l0; if (cur > 32) cur = 32;
#pragma unroll
        for (int t = 0; t < 2; ++t) {
            int idx = tid + t * 256;             // W: 48*8 = 384 float4
            wr[t] = make_float4(0.f, 0.f, 0.f, 0.f);
            if (idx < 384) {
                int p = idx >> 3, l4 = (idx & 7) * 4;
                if (l4 < cur) wr[t] = *(const float4*)&Wn[(size_t)p * L_ + l0 + l4];
            }
        }
#pragma unroll
        for (int t = 0; t < 2; ++t) {
            int idx = tid + t * 256;             // B: 64*8 = 512 float4
            int bb = idx >> 3, l4 = (idx & 7) * 4;
            br[t] = (l4 < cur) ? *(const float4*)&trT[(size_t)bb * L_ + l0 + l4]
                               : make_float4(0.f, 0.f, 0.f, 0.f);
        }
    };
    auto stage = [&]() {
#pragma unroll
        for (int t = 0; t < 2; ++t) {
            int idx = tid + t * 256;
            if (idx < 384) *(float4*)&Wl[(idx >> 3) * 36 + (idx & 7) * 4] = wr[t];
        }
#pragma unroll
        for (int t = 0; t < 2; ++t) {
            int idx = tid + t * 256;
            *(float4*)&Bl[(idx >> 3) * 36 + (idx & 7) * 4] = br[t];
        }
    };
    auto compute = [&]() {
        for (int lc = 0; lc < 32; lc += 4) {
            float4 wv[3], bv[4];
#pragma unroll
            for (int j = 0; j < 3; ++j) wv[j] = *(const float4*)&Wl[(pt + 16 * j) * 36 + lc];
#pragma unroll
            for (int i = 0; i < 4; ++i) bv[i] = *(const float4*)&Bl[(btl + 16 * i) * 36 + lc];
#pragma unroll
            for (int j = 0; j < 3; ++j)
#pragma unroll
                for (int i = 0; i < 4; ++i)
                    acc[j][i] += wv[j].x * bv[i].x + wv[j].y * bv[i].y +
                                 wv[j].z * bv[i].z + wv[j].w * bv[i].w;
        }
    };

    fetch(0);
    stage();
    for (int l0 = 32; l0 < L_; l0 += 32) {       // chunks: 15x32 + 8
        fetch(l0);
        __syncthreads();
        compute();
        __syncthreads();
        stage();
    }
    __syncthreads();
    compute();

    // stage C (48x64) into LDS, write coalesced to disjoint partial region
    float* Cst = smem;
    __syncthreads();
#pragma unroll
    for (int j = 0; j < 3; ++j)
#pragma unroll
        for (int i = 0; i < 4; ++i)
            Cst[(pt + 16 * j) * 64 + (btl + 16 * i)] = acc[j][i];
    __syncthreads();
    float4* dst = (float4*)(part + ((size_t)n * P_ + (size_t)ptb * 48) * B_);
    const float4* src = (const float4*)Cst;
    for (int i = tid; i < 768; i += 256) dst[i] = src[i];
}

// ------- Kernel 4: transpose partial[n][p][b] + bias -> out0 [b][p][n] -----
__global__ __launch_bounds__(256) void k_reduce_trend(const float* __restrict__ part,
                                                      const float* __restrict__ bt,
                                                      float* __restrict__ out0) {
    int nt = blockIdx.x, p = blockIdx.y, tid = threadIdx.x;
    __shared__ float t[32][65];
    int n0 = nt * 32;
    for (int idx = tid; idx < 2048; idx += 256) {
        int i = idx >> 6, j = idx & 63;
        t[i][j] = part[(size_t)(n0 + i) * PB_ + p * 64 + j];
    }
    __syncthreads();
    for (int idx = tid; idx < 2048; idx += 256) {
        int bb = idx >> 5, nl = idx & 31;
        out0[((size_t)bb * P_ + p) * N_ + n0 + nl] = t[nl][bb] + bt[(size_t)p * N_ + n0 + nl];
    }
}

// ---------------- Kernel 5: season attention scores ----------------
__global__ __launch_bounds__(256) void k_season_scores(float* ws) {
    int b = blockIdx.x, kt = blockIdx.y, tid = threadIdx.x;
    const float* EN = ws + OFF_EN + (size_t)b * P_ * D_;
    const float* ET = ws + OFF_ET + (size_t)b * L_ * D_;
    float* W = ws + OFF_WSE + (size_t)b * P_ * L_;
    __shared__ float Al[96][68];
    __shared__ float Bl[64][68];
    for (int idx = tid; idx < 96 * 16; idx += 256) {
        int q = idx >> 4, d4 = (idx & 15) * 4;
        *(float4*)&Al[q][d4] = *(const float4*)&EN[q * 64 + d4];
    }
    int k0 = kt * 64;
    for (int idx = tid; idx < 64 * 16; idx += 256) {
        int kk = idx >> 4, d4 = (idx & 15) * 4;
        float4 v = (k0 + kk < L_) ? *(const float4*)&ET[(size_t)(k0 + kk) * D_ + d4]
                                  : make_float4(0.f, 0.f, 0.f, 0.f);
        *(float4*)&Bl[kk][d4] = v;
    }
    __syncthreads();
    int qt = tid >> 4, ktl = tid & 15;
    float acc[6][4] = {};
    for (int d = 0; d < 64; d += 4) {
        float4 av[6], bv[4];
#pragma unroll
        for (int j = 0; j < 6; ++j) av[j] = *(const float4*)&Al[qt + 16 * j][d];
#pragma unroll
        for (int i = 0; i < 4; ++i) bv[i] = *(const float4*)&Bl[ktl + 16 * i][d];
#pragma unroll
        for (int j = 0; j < 6; ++j)
#pragma unroll
            for (int i = 0; i < 4; ++i)
                acc[j][i] += av[j].x * bv[i].x + av[j].y * bv[i].y +
                             av[j].z * bv[i].z + av[j].w * bv[i].w;
    }
#pragma unroll
    for (int j = 0; j < 6; ++j) {
        int q = qt + 16 * j;
#pragma unroll
        for (int i = 0; i < 4; ++i) {
            int k = k0 + ktl + 16 * i;
            if (k < L_) W[(size_t)q * L_ + k] = acc[j][i] * 0.125f;
        }
    }
}

// ------- Kernel 6: one-wave-per-row softmax over L_ ----
__global__ __launch_bounds__(64) void k_softmax_rows(float* __restrict__ base_g) {
    float* base = base_g + (size_t)blockIdx.x * L_;
    int lane = threadIdx.x;
    float v[8];
    float m = -FLT_MAX;
#pragma unroll
    for (int i = 0; i < 8; ++i) {
        int idx = i * 64 + lane;
        v[i] = (idx < L_) ? base[idx] : -FLT_MAX;
        m = fmaxf(m, v[i]);
    }
    for (int off = 32; off; off >>= 1) m = fmaxf(m, __shfl_xor(m, off));
    float s = 0.f;
#pragma unroll
    for (int i = 0; i < 8; ++i) {
        float e = expf(v[i] - m);
        v[i] = e; s += e;
    }
    for (int off = 32; off; off >>= 1) s += __shfl_xor(s, off);
    float inv = 1.f / s;
#pragma unroll
    for (int i = 0; i < 8; ++i) {
        int idx = i * 64 + lane;
        if (idx < L_) base[idx] = v[i] * inv;
    }
}

// ------- Kernel 7: mid masked raw scores, grid (B, 8 k-tiles) ----------
__global__ __launch_bounds__(256) void k_mid_scores(float* ws) {
    int b = blockIdx.x, kt = blockIdx.y, tid = threadIdx.x;
    const float* ET = ws + OFF_ET + (size_t)b * L_ * D_;
    float* WM = ws + OFF_WM + (size_t)b * MID_ * L_;
    __shared__ float qv[7][68];
    __shared__ float Bl[64 * 65];
    for (int idx = tid; idx < 7 * 16; idx += 256) {
        int q = idx >> 4, d4 = (idx & 15) * 4;
        *(float4*)&qv[q][d4] = *(const float4*)&ET[(size_t)(L_ - MID_ + q) * D_ + d4];
    }
    int k0 = kt * 64;
    for (int idx = tid; idx < 64 * 16; idx += 256) {
        int kk = idx >> 4, d4 = (idx & 15) * 4;
        float4 v = (k0 + kk < L_) ? *(const float4*)&ET[(size_t)(k0 + kk) * D_ + d4]
                                  : make_float4(0.f, 0.f, 0.f, 0.f);
        Bl[kk * 65 + d4 + 0] = v.x;
        Bl[kk * 65 + d4 + 1] = v.y;
        Bl[kk * 65 + d4 + 2] = v.z;
        Bl[kk * 65 + d4 + 3] = v.w;
    }
    __syncthreads();
    int klane = tid & 63, qs = tid >> 6;
    int q0 = qs, q1 = qs + 4;
    float a0 = 0.f, a1 = 0.f;
    for (int d = 0; d < 64; ++d) {
        float e = Bl[klane * 65 + d];
        a0 += e * qv[q0][d];
        if (q1 < 7) a1 += e * qv[q1][d];
    }
    int k = k0 + klane;
    if (k < L_) {
        WM[(size_t)q0 * L_ + k] = (k < L_ - MID_ + q0) ? a0 * 0.125f : -FLT_MAX;
        if (q1 < 7)
            WM[(size_t)q1 * L_ + k] = (k < L_ - MID_ + q1) ? a1 * 0.125f : -FLT_MAX;
    }
}

// ------- Kernel 8: season PV, q-split x2 (NO atomics), pipelined ----------
// grid (B, 4 n-tiles, 2 q-tiles of 48), block 256. out0 holds pred_trend.
__global__ __launch_bounds__(256) void k_season_pv(const float* __restrict__ ws_c,
                                                   float* __restrict__ out0) {
    int b = blockIdx.x, nt = blockIdx.y, qt = blockIdx.z, tid = threadIdx.x;
    const float* Wb = ws_c + OFF_WSE + ((size_t)b * P_ + (size_t)qt * 48) * L_;
    const float* Xs = ws_c + OFF_XS + (size_t)b * L_ * N_;
    __shared__ float Wl[48][36];
    __shared__ float Xl[32][68];
    int pt = tid >> 4, ntl = tid & 15;
    float acc[3][4] = {};
    float4 wr[2], xr[2];

    auto fetch = [&](int k0) {
        int cur = L_ - k0; if (cur > 32) cur = 32;
#pragma unroll
        for (int t = 0; t < 2; ++t) {
            int idx = tid + t * 256;             // W: 48*8 = 384 float4
            wr[t] = make_float4(0.f, 0.f, 0.f, 0.f);
            if (idx < 384) {
                int q = idx >> 3, l4 = (idx & 7) * 4;
                if (l4 < cur) wr[t] = *(const float4*)&Wb[(size_t)q * L_ + k0 + l4];
            }
        }
#pragma unroll
        for (int t = 0; t < 2; ++t) {
            int idx = tid + t * 256;             // X: 32*16 = 512 float4
            int kc = idx >> 4, n4 = (idx & 15) * 4;
            xr[t] = (kc < cur) ? *(const float4*)&Xs[(size_t)(k0 + kc) * N_ + nt * 64 + n4]
                               : make_float4(0.f, 0.f, 0.f, 0.f);
        }
    };
    auto stage = [&]() {
#pragma unroll
        for (int t = 0; t < 2; ++t) {
            int idx = tid + t * 256;
            if (idx < 384) *(float4*)&Wl[idx >> 3][(idx & 7) * 4] = wr[t];
        }
#pragma unroll
        for (int t = 0; t < 2; ++t) {
            int idx = tid + t * 256;
            *(float4*)&Xl[idx >> 4][(idx & 15) * 4] = xr[t];
        }
    };
    auto compute = [&]() {
        for (int kc = 0; kc < 32; kc += 4) {
            float4 wv[3];
#pragma unroll
            for (int j = 0; j < 3; ++j) wv[j] = *(const float4*)&Wl[pt + 16 * j][kc];
#pragma unroll
            for (int t = 0; t < 4; ++t) {
                float4 xv = *(const float4*)&Xl[kc + t][ntl * 4];
#pragma unroll
                for (int j = 0; j < 3; ++j) {
                    float w = (t == 0) ? wv[j].x : (t == 1) ? wv[j].y : (t == 2) ? wv[j].z : wv[j].w;
                    acc[j][0] += w * xv.x;
                    acc[j][1] += w * xv.y;
                    acc[j][2] += w * xv.z;
                    acc[j][3] += w * xv.w;
                }
            }
        }
    };

    fetch(0);
    stage();
    for (int k0 = 32; k0 < L_; k0 += 32) {       // chunks: 15x32 + 8
        fetch(k0);
        __syncthreads();
        compute();
        __syncthreads();
        stage();
    }
    __syncthreads();
    compute();

#pragma unroll
    for (int j = 0; j < 3; ++j) {
        int q = qt * 48 + pt + 16 * j;
        float4* basep = (float4*)&out0[((size_t)b * P_ + q) * N_ + nt * 64 + ntl * 4];
        float4 prev = *basep;
        prev.x += acc[j][0]; prev.y += acc[j][1];
        prev.z += acc[j][2]; prev.w += acc[j][3];
        *basep = prev;
    }
}

// ------- Kernel 9: mid PV -> out1, 8-way k-slices in one block -------------
__global__ __launch_bounds__(512) void k_mid_pv(const float* __restrict__ ws_c,
                                                float* __restrict__ out1) {
    int b = blockIdx.x, nt = blockIdx.y, tid = threadIdx.x;
    int nl = tid & 63, ks = tid >> 6;
    const float* Xs = ws_c + OFF_XS + (size_t)b * L_ * N_;
    const float* WM = ws_c + OFF_WM + (size_t)b * MID_ * L_;
    __shared__ float wl[7 * L_];
    __shared__ float part[8][7][64];
    for (int idx = tid; idx < 7 * L_; idx += 512) wl[idx] = WM[idx];
    __syncthreads();
    float acc[7] = {};
    int kbeg = ks * 61, kend = kbeg + 61;
    for (int k = kbeg; k < kend; ++k) {
        float xv = Xs[(size_t)k * N_ + nt * 64 + nl];
#pragma unroll
        for (int q = 0; q < 7; ++q) acc[q] += wl[q * L_ + k] * xv;
    }
#pragma unroll
    for (int q = 0; q < 7; ++q) part[ks][q][nl] = acc[q];
    __syncthreads();
    if (ks == 0) {
#pragma unroll
        for (int q = 0; q < 7; ++q) {
            float v = 0.f;
#pragma unroll
            for (int s = 0; s < 8; ++s) v += part[s][q][nl];
            out1[((size_t)b * MID_ + q) * N_ + nt * 64 + nl] = v;
        }
    }
}

extern "C" void kernel_launch(void* const* d_in, const int* in_sizes, int n_in,
                              void* d_out, int out_size, void* d_ws, size_t ws_size,
                              hipStream_t stream) {
    (void)in_sizes; (void)n_in; (void)out_size; (void)ws_size;
    const float* X  = (const float*)d_in[0];
    const float* T  = (const float*)d_in[1];
    const float* Wt = (const float*)d_in[2];
    const float* bt = (const float*)d_in[3];
    const float* w0 = (const float*)d_in[4];
    const float* b0 = (const float*)d_in[5];
    const float* Wp = (const float*)d_in[6];
    const float* Bp = (const float*)d_in[7];
    float* out = (float*)d_out;
    float* ws  = (float*)d_ws;
    float* out1 = out + (size_t)B_ * P_ * N_;

    hipLaunchKernelGGL(k_trend, dim3(B_, 8), dim3(256), 0, stream, X, ws);
    hipLaunchKernelGGL(k_embed, dim3((B_ * (L_ + P_) * D_) / 256), dim3(256), 0, stream,
                       T, w0, b0, Wp, Bp, ws);
    hipLaunchKernelGGL(k_trend_gemm, dim3(N_, 2), dim3(256), 0, stream, Wt, ws, ws + OFF_PART);
    hipLaunchKernelGGL(k_reduce_trend, dim3(8, 96), dim3(256), 0, stream, ws + OFF_PART, bt, out);
    hipLaunchKernelGGL(k_season_scores, dim3(B_, 8), dim3(256), 0, stream, ws);
    hipLaunchKernelGGL(k_softmax_rows, dim3(B_ * P_), dim3(64), 0, stream, ws + OFF_WSE);
    hipLaunchKernelGGL(k_mid_scores, dim3(B_, 8), dim3(256), 0, stream, ws);
    hipLaunchKernelGGL(k_softmax_rows, dim3(B_ * MID_), dim3(64), 0, stream, ws + OFF_WM);
    hipLaunchKernelGGL(k_season_pv, dim3(B_, 4, 2), dim3(256), 0, stream, ws, out);
    hipLaunchKernelGGL(k_mid_pv, dim3(B_, 4), dim3(512), 0, stream, ws, out1);
}